// Round 1
// baseline (17923.526 us; speedup 1.0000x reference)
//
#include <hip/hip_runtime.h>
#include <hip/hip_bf16.h>
#include <math.h>

#define DD   256
#define FFD  512
#define NH   4
#define KS   8
#define LL   64
#define NCC  32768
#define SB   260   // padded stride for 256-wide LDS rows
#define HB   772   // padded stride for 768-wide LDS rows

__device__ __forceinline__ float gelu_f(float x) {
    return x * 0.5f * (1.0f + erff(x * 0.70710678118654752f));
}

// Detect mask storage format: 0 = int32 {0,1}, 1 = byte-packed, 2 = float32 {0,1.0f}
__global__ void detect_mask_fmt(const unsigned int* __restrict__ mw, int nwords, int* __restrict__ flag) {
    __shared__ int s_bad_int, s_bad_float;
    if (threadIdx.x == 0) { s_bad_int = 0; s_bad_float = 0; }
    __syncthreads();
    int bad_int = 0, bad_float = 0;
    for (int i = threadIdx.x; i < nwords; i += blockDim.x) {
        unsigned int w = mw[i];
        if (w > 1u) bad_int = 1;
        if (w != 0u && w != 0x3F800000u) bad_float = 1;
    }
    if (bad_int)   atomicOr(&s_bad_int, 1);
    if (bad_float) atomicOr(&s_bad_float, 1);
    __syncthreads();
    if (threadIdx.x == 0)
        *flag = (!s_bad_int) ? 0 : ((!s_bad_float) ? 2 : 1);
}

__device__ __forceinline__ void block_layernorm(const float (&in)[KS][SB], float (&out)[KS][SB],
                                                const float* __restrict__ w, const float* __restrict__ b,
                                                int tid) {
    int wv = tid >> 6, ln = tid & 63;
    for (int rr = 0; rr < 2; rr++) {
        int r = wv + rr * 4;
        float s = 0.f, sq = 0.f;
        #pragma unroll
        for (int j0 = 0; j0 < 4; j0++) {
            float x = in[r][ln + 64 * j0];
            s += x; sq += x * x;
        }
        #pragma unroll
        for (int off = 32; off; off >>= 1) {
            s  += __shfl_xor(s, off);
            sq += __shfl_xor(sq, off);
        }
        float mu  = s * (1.0f / DD);
        float var = sq * (1.0f / DD) - mu * mu;
        float rs  = rsqrtf(var + 1e-5f);
        #pragma unroll
        for (int j0 = 0; j0 < 4; j0++) {
            int j = ln + 64 * j0;
            float x = in[r][j];
            out[r][j] = (x - mu) * rs * w[j] + b[j];
        }
    }
}

// dot of LDS row (stride-SB or HB) with a 16B-aligned global row, length n (multiple of 4)
__device__ __forceinline__ float dot_row4(const float* __restrict__ lrow, const float* __restrict__ grow, int n) {
    const float4* w4 = reinterpret_cast<const float4*>(grow);
    float s0 = 0.f, s1 = 0.f, s2 = 0.f, s3 = 0.f;
    #pragma unroll 8
    for (int d4 = 0; d4 < (n >> 2); d4++) {
        float4 wv = w4[d4];
        const float* hr = lrow + d4 * 4;
        s0 = fmaf(hr[0], wv.x, s0);
        s1 = fmaf(hr[1], wv.y, s1);
        s2 = fmaf(hr[2], wv.z, s2);
        s3 = fmaf(hr[3], wv.w, s3);
    }
    return (s0 + s1) + (s2 + s3);
}

__global__ __launch_bounds__(256)
void tsa_main(const float* __restrict__ v,
              const int* __restrict__ batch_idx,
              const void* __restrict__ mask,
              const float* __restrict__ count,
              const float* __restrict__ pos_embed,
              const float* __restrict__ ln1_w, const float* __restrict__ ln1_b,
              const float* __restrict__ in_proj_w, const float* __restrict__ in_proj_b,
              const float* __restrict__ out_proj_w, const float* __restrict__ out_proj_b,
              const float* __restrict__ ln2_w, const float* __restrict__ ln2_b,
              const float* __restrict__ ff1_w, const float* __restrict__ ff1_b,
              const float* __restrict__ ff2_w, const float* __restrict__ ff2_b,
              const float* __restrict__ o1_w, const float* __restrict__ o1_b,
              const float* __restrict__ o2_w, const float* __restrict__ o2_b,
              const int* __restrict__ mask_flag,
              float* __restrict__ out)
{
    __shared__ float xbuf[KS][SB];
    __shared__ float sbuf[KS][SB];
    __shared__ float hbuf[KS][HB];
    __shared__ float attbuf[NH][KS][KS];
    __shared__ float featbuf[DD + 1];
    __shared__ float g1buf[FFD];
    __shared__ int s_idx[KS];
    __shared__ int s_m;

    const int c   = blockIdx.x;
    const int tid = threadIdx.x;

    // ---- parse mask: first up-to-8 set positions, ascending ----
    if (tid < 64) {
        int mf = *mask_flag;
        int bit;
        if (mf == 0)      bit = ((const int*)mask)[(size_t)c * LL + tid] != 0;
        else if (mf == 2) bit = ((const float*)mask)[(size_t)c * LL + tid] != 0.0f;
        else              bit = ((const unsigned char*)mask)[(size_t)c * LL + tid] != 0;
        unsigned long long bal = __ballot(bit);
        if (tid == 0) {
            int mm = 0;
            unsigned long long b = bal;
            while (b && mm < KS) {
                int p = __ffsll(b) - 1;
                s_idx[mm++] = p;
                b &= (b - 1);
            }
            for (int i2 = mm; i2 < KS; i2++) s_idx[i2] = 0;
            s_m = mm;
        }
    }
    __syncthreads();
    const int m = s_m;

    if (m > 0) {
        // ---- gather + pos embed ----
        const int bi = batch_idx[c];
        const float* vb = v + ((size_t)bi * LL) * DD;
        #pragma unroll
        for (int r = 0; r < KS; r++) {
            float pe  = pos_embed[r * DD + tid];
            float val = (r < m) ? vb[(size_t)s_idx[r] * DD + tid] : 0.0f;
            xbuf[r][tid] = val + pe;
        }
        __syncthreads();

        // ---- LN1 -> sbuf ----
        block_layernorm(xbuf, sbuf, ln1_w, ln1_b, tid);
        __syncthreads();

        // ---- QKV: hbuf[r][0:768] = sbuf[r] @ in_proj_w.T + b ----
        for (int i = 0; i < 24; i++) {
            int f = i * 256 + tid;
            int o = f >> 3;
            int r = f & 7;
            float s = dot_row4(&sbuf[r][0], in_proj_w + (size_t)o * DD, DD);
            hbuf[r][o] = s + in_proj_b[o];
        }
        __syncthreads();

        // ---- attention scores + softmax (thread = (h, q-row, key)) ----
        {
            int hh = tid >> 6;
            int r  = (tid >> 3) & 7;
            int j  = tid & 7;
            int ho = hh * 64;
            float s = 0.0f;
            #pragma unroll 8
            for (int d = 0; d < 64; d++)
                s = fmaf(hbuf[r][ho + d], hbuf[j][DD + ho + d], s);
            float a = s * 0.125f;
            if (j >= m) a = -1e30f;
            float mx = a;
            mx = fmaxf(mx, __shfl_xor(mx, 1));
            mx = fmaxf(mx, __shfl_xor(mx, 2));
            mx = fmaxf(mx, __shfl_xor(mx, 4));
            float e = (j >= m) ? 0.0f : expf(a - mx);
            float se = e;
            se += __shfl_xor(se, 1);
            se += __shfl_xor(se, 2);
            se += __shfl_xor(se, 4);
            attbuf[hh][r][j] = e / se;
        }
        __syncthreads();

        // ---- ao = att @ V -> sbuf (col = tid = h*64+d) ----
        {
            int hh = tid >> 6;
            #pragma unroll
            for (int r = 0; r < KS; r++) {
                float s = 0.0f;
                #pragma unroll
                for (int j = 0; j < KS; j++)
                    s = fmaf(attbuf[hh][r][j], hbuf[j][2 * DD + tid], s);
                sbuf[r][tid] = s;
            }
        }
        __syncthreads();

        // ---- out_proj + residual into xbuf ----
        for (int i = 0; i < 8; i++) {
            int f = i * 256 + tid;
            int o = f >> 3;
            int r = f & 7;
            float s = dot_row4(&sbuf[r][0], out_proj_w + (size_t)o * DD, DD);
            xbuf[r][o] += s + out_proj_b[o];
        }
        __syncthreads();

        // ---- LN2 -> sbuf ----
        block_layernorm(xbuf, sbuf, ln2_w, ln2_b, tid);
        __syncthreads();

        // ---- FF1 (gelu) -> hbuf[r][0:512] ----
        for (int i = 0; i < 16; i++) {
            int f = i * 256 + tid;
            int o = f >> 3;   // 0..511
            int r = f & 7;
            float s = dot_row4(&sbuf[r][0], ff1_w + (size_t)o * DD, DD);
            hbuf[r][o] = gelu_f(s + ff1_b[o]);
        }
        __syncthreads();

        // ---- FF2 + residual into xbuf ----
        for (int i = 0; i < 8; i++) {
            int f = i * 256 + tid;
            int o = f >> 3;
            int r = f & 7;
            float s = dot_row4(&hbuf[r][0], ff2_w + (size_t)o * FFD, FFD);
            xbuf[r][o] += s + ff2_b[o];
        }
        __syncthreads();

        // ---- masked mean pool ----
        {
            float p = 0.0f;
            for (int r = 0; r < m; r++) p += xbuf[r][tid];
            featbuf[tid] = p / (float)m;
        }
    } else {
        featbuf[tid] = 0.0f;
    }
    if (tid == 0) featbuf[DD] = log1pf(count[c]);
    __syncthreads();

    // ---- head: g1 = gelu(feat @ o1_w.T + o1_b) ----
    for (int i = 0; i < 2; i++) {
        int o = i * 256 + tid;
        const float* wr = o1_w + (size_t)o * (DD + 1);
        float s0 = 0.f, s1 = 0.f;
        #pragma unroll 4
        for (int d = 0; d < DD; d += 2) {
            s0 = fmaf(featbuf[d], wr[d], s0);
            s1 = fmaf(featbuf[d + 1], wr[d + 1], s1);
        }
        float s = s0 + s1 + featbuf[DD] * wr[DD];
        g1buf[o] = gelu_f(s + o1_b[o]);
    }
    __syncthreads();

    // ---- head: out = g1 @ o2_w.T + o2_b ----
    {
        float s = dot_row4(&g1buf[0], o2_w + (size_t)tid * FFD, FFD);
        out[(size_t)c * DD + tid] = s + o2_b[tid];
    }
}

extern "C" void kernel_launch(void* const* d_in, const int* in_sizes, int n_in,
                              void* d_out, int out_size, void* d_ws, size_t ws_size,
                              hipStream_t stream) {
    const float* v          = (const float*)d_in[0];
    const int*   batch_idx  = (const int*)d_in[1];
    const void*  mask       = d_in[2];
    const float* count      = (const float*)d_in[3];
    const float* pos_embed  = (const float*)d_in[4];
    const float* ln1_w      = (const float*)d_in[5];
    const float* ln1_b      = (const float*)d_in[6];
    const float* in_proj_w  = (const float*)d_in[7];
    const float* in_proj_b  = (const float*)d_in[8];
    const float* out_proj_w = (const float*)d_in[9];
    const float* out_proj_b = (const float*)d_in[10];
    const float* ln2_w      = (const float*)d_in[11];
    const float* ln2_b      = (const float*)d_in[12];
    const float* ff1_w      = (const float*)d_in[13];
    const float* ff1_b      = (const float*)d_in[14];
    const float* ff2_w      = (const float*)d_in[15];
    const float* ff2_b      = (const float*)d_in[16];
    const float* o1_w       = (const float*)d_in[17];
    const float* o1_b       = (const float*)d_in[18];
    const float* o2_w       = (const float*)d_in[19];
    const float* o2_b       = (const float*)d_in[20];
    float* out = (float*)d_out;
    int* flag  = (int*)d_ws;

    detect_mask_fmt<<<1, 256, 0, stream>>>((const unsigned int*)mask, 16384, flag);
    tsa_main<<<NCC, 256, 0, stream>>>(v, batch_idx, mask, count, pos_embed,
                                      ln1_w, ln1_b, in_proj_w, in_proj_b,
                                      out_proj_w, out_proj_b, ln2_w, ln2_b,
                                      ff1_w, ff1_b, ff2_w, ff2_b,
                                      o1_w, o1_b, o2_w, o2_b, flag, out);
}

// Round 2
// 2457.662 us; speedup vs baseline: 7.2929x; 7.2929x over previous
//
#include <hip/hip_runtime.h>
#include <hip/hip_bf16.h>
#include <math.h>

typedef short short8 __attribute__((ext_vector_type(8)));
typedef float f32x4 __attribute__((ext_vector_type(4)));

#define NCC  32768
#define G    2          // chunks per main block
#define ROWS 16         // G*8
#define AST  264        // abuf stride (bf16 elems)
#define QST  776        // qkv/gff stride (bf16 elems)
#define XST  257        // xres stride (floats)

// weight region offsets in d_ws (bf16 elems)
#define W1_OFF 0
#define W2_OFF 196608
#define W3_OFF 262144
#define W4_OFF 393216
#define W_TOTAL 524288

__device__ __forceinline__ float gelu_f(float x) {
    return x * 0.5f * (1.0f + erff(x * 0.70710678118654752f));
}
__device__ __forceinline__ float bf2f(unsigned short u) {
    union { unsigned int i; float f; } w; w.i = ((unsigned int)u) << 16; return w.f;
}
__device__ __forceinline__ unsigned short f2bf(float f) {
    __hip_bfloat16 h = __float2bfloat16(f);   // round-to-nearest-even
    return *reinterpret_cast<unsigned short*>(&h);
}

// ---- one-time weight f32->bf16 conversion into d_ws ----
__global__ void conv_weights(const float* __restrict__ w1, const float* __restrict__ w2,
                             const float* __restrict__ w3, const float* __restrict__ w4,
                             unsigned short* __restrict__ dst) {
    int i = blockIdx.x * 256 + threadIdx.x;
    float v;
    if (i < W2_OFF)        v = w1[i];
    else if (i < W3_OFF)   v = w2[i - W2_OFF];
    else if (i < W4_OFF)   v = w3[i - W3_OFF];
    else                   v = w4[i - W4_OFF];
    dst[i] = f2bf(v);
}

// ---- mask storage format detect: 0=int32, 1=byte, 2=float32 ----
__global__ void detect_mask_fmt(const unsigned int* __restrict__ mw, int nwords, int* __restrict__ flag) {
    __shared__ int s_bad_int, s_bad_float;
    if (threadIdx.x == 0) { s_bad_int = 0; s_bad_float = 0; }
    __syncthreads();
    int bad_int = 0, bad_float = 0;
    for (int i = threadIdx.x; i < nwords; i += blockDim.x) {
        unsigned int w = mw[i];
        if (w > 1u) bad_int = 1;
        if (w != 0u && w != 0x3F800000u) bad_float = 1;
    }
    if (bad_int)   atomicOr(&s_bad_int, 1);
    if (bad_float) atomicOr(&s_bad_float, 1);
    __syncthreads();
    if (threadIdx.x == 0)
        *flag = (!s_bad_int) ? 0 : ((!s_bad_float) ? 2 : 1);
}

// ===================== main transformer kernel (2 chunks/block) =====================
__global__ __launch_bounds__(256)
void tsa_main(const float* __restrict__ v,
              const int* __restrict__ batch_idx,
              const void* __restrict__ mask,
              const float* __restrict__ pos_embed,
              const float* __restrict__ ln1_w, const float* __restrict__ ln1_b,
              const float* __restrict__ in_proj_b,
              const float* __restrict__ out_proj_b,
              const float* __restrict__ ln2_w, const float* __restrict__ ln2_b,
              const float* __restrict__ ff1_b, const float* __restrict__ ff2_b,
              const unsigned short* __restrict__ wb,
              const int* __restrict__ mask_flag,
              float* __restrict__ out)   // out rows temporarily hold pooled features
{
    __shared__ float xres[ROWS][XST];              // residual stream (f32)
    __shared__ unsigned short abuf[ROWS][AST];     // GEMM A input (bf16): X_ln / ao / h2ln
    __shared__ unsigned short qkv[ROWS][QST];      // qkv (768) then gff (512)
    __shared__ float attw[G][4][8][8];
    __shared__ int s_idx[G][8];
    __shared__ int s_m[G];

    const int tid  = threadIdx.x;
    const int lane = tid & 63;
    const int wid  = tid >> 6;
    const int cg0  = blockIdx.x * G;

    // ---- mask parse: wave w handles chunk w ----
    if (wid < G) {
        int mf = *mask_flag;
        size_t base = (size_t)(cg0 + wid) * 64 + lane;
        int bit;
        if (mf == 0)      bit = ((const int*)mask)[base] != 0;
        else if (mf == 2) bit = ((const float*)mask)[base] != 0.0f;
        else              bit = ((const unsigned char*)mask)[base] != 0;
        unsigned long long bal = __ballot(bit);
        if (lane == 0) {
            int mm = 0; unsigned long long b = bal;
            while (b && mm < 8) { s_idx[wid][mm++] = __ffsll(b) - 1; b &= (b - 1); }
            for (int t = mm; t < 8; t++) s_idx[wid][t] = 0;
            s_m[wid] = mm;
        }
    }
    __syncthreads();

    // ---- gather + pos embed -> xres ----
    {
        int bi0 = batch_idx[cg0 + 0];
        int bi1 = batch_idx[cg0 + 1];
        #pragma unroll
        for (int r = 0; r < ROWS; r++) {
            int c = r >> 3, rr = r & 7;
            int bi = c ? bi1 : bi0;
            float val = 0.0f;
            if (rr < s_m[c])
                val = v[((size_t)bi * 64 + s_idx[c][rr]) * 256 + tid];
            xres[r][tid] = val + pos_embed[rr * 256 + tid];
        }
    }
    __syncthreads();

    // ---- layernorm helper: xres -> abuf (bf16). 4 rows/wave, 16 lanes/row ----
    auto do_ln = [&](const float* lw, const float* lb) {
        int r  = wid * 4 + (lane >> 4);
        int c0 = lane & 15;
        float vals[16];
        float s = 0.f, sq = 0.f;
        #pragma unroll
        for (int t = 0; t < 16; t++) {
            float x = xres[r][c0 + 16 * t];
            vals[t] = x; s += x; sq += x * x;
        }
        #pragma unroll
        for (int off = 1; off < 16; off <<= 1) {
            s  += __shfl_xor(s, off);
            sq += __shfl_xor(sq, off);
        }
        float mu  = s * (1.0f / 256.0f);
        float var = sq * (1.0f / 256.0f) - mu * mu;
        float rs  = rsqrtf(var + 1e-5f);
        #pragma unroll
        for (int t = 0; t < 16; t++) {
            int j = c0 + 16 * t;
            abuf[r][j] = f2bf((vals[t] - mu) * rs * lw[j] + lb[j]);
        }
    };

    auto load_afr = [&](short8* afr, const unsigned short* base, int stride, int nk) {
        int row = lane & 15;
        int ko  = (lane >> 4) * 8;
        for (int kt = 0; kt < nk; kt++)
            afr[kt] = *reinterpret_cast<const short8*>(base + row * stride + kt * 32 + ko);
    };

    // ---- LN1 ----
    do_ln(ln1_w, ln1_b);
    __syncthreads();

    const int rb = (lane >> 4) * 4;   // C-frag row base

    // ---- GEMM1: qkv = X_ln @ W1^T + b1 (N=768, K=256) ----
    {
        short8 afr[8];
        load_afr(afr, &abuf[0][0], AST, 8);
        int n0 = wid * 192;
        for (int nt = 0; nt < 12; nt++) {
            int col = n0 + nt * 16 + (lane & 15);
            const unsigned short* wrow = wb + W1_OFF + (size_t)col * 256 + (lane >> 4) * 8;
            f32x4 acc = {0.f, 0.f, 0.f, 0.f};
            #pragma unroll
            for (int kt = 0; kt < 8; kt++) {
                short8 bfr = *reinterpret_cast<const short8*>(wrow + kt * 32);
                acc = __builtin_amdgcn_mfma_f32_16x16x32_bf16(afr[kt], bfr, acc, 0, 0, 0);
            }
            float bias = in_proj_b[col];
            #pragma unroll
            for (int r = 0; r < 4; r++)
                qkv[rb + r][col] = f2bf(acc[r] + bias);
        }
    }
    __syncthreads();

    // ---- attention scores + softmax ----
    {
        int c  = tid >> 7;
        int h  = (tid >> 5) & 3;
        int qp = (tid >> 3) & 3;
        int j  = tid & 7;
        int m  = s_m[c];
        const unsigned short* krow = &qkv[c * 8 + j][256 + h * 64];
        #pragma unroll
        for (int qq = 0; qq < 2; qq++) {
            int q = qp + qq * 4;
            const unsigned short* qrow = &qkv[c * 8 + q][h * 64];
            float s = 0.f;
            #pragma unroll
            for (int d = 0; d < 64; d += 8) {
                short8 qv = *reinterpret_cast<const short8*>(qrow + d);
                short8 kv = *reinterpret_cast<const short8*>(krow + d);
                #pragma unroll
                for (int t = 0; t < 8; t++)
                    s = fmaf(bf2f((unsigned short)qv[t]), bf2f((unsigned short)kv[t]), s);
            }
            float a = s * 0.125f;
            if (j >= m) a = -1e30f;
            float mx = a;
            mx = fmaxf(mx, __shfl_xor(mx, 1));
            mx = fmaxf(mx, __shfl_xor(mx, 2));
            mx = fmaxf(mx, __shfl_xor(mx, 4));
            float e = (j < m) ? expf(a - mx) : 0.f;
            float se = e;
            se += __shfl_xor(se, 1);
            se += __shfl_xor(se, 2);
            se += __shfl_xor(se, 4);
            attw[c][h][q][j] = (se > 0.f) ? e / se : 0.f;
        }
    }
    __syncthreads();

    // ---- ao = att @ V -> abuf (bf16) ----
    {
        int c  = tid >> 7;
        int d0 = (tid & 127) * 2;
        int h  = d0 >> 6;
        #pragma unroll
        for (int q = 0; q < 8; q++) {
            float a0 = 0.f, a1 = 0.f;
            #pragma unroll
            for (int j = 0; j < 8; j++) {
                float a = attw[c][h][q][j];
                unsigned int vv = *reinterpret_cast<const unsigned int*>(&qkv[c * 8 + j][512 + d0]);
                a0 = fmaf(a, bf2f((unsigned short)(vv & 0xffffu)), a0);
                a1 = fmaf(a, bf2f((unsigned short)(vv >> 16)), a1);
            }
            unsigned int pk = (unsigned int)f2bf(a0) | ((unsigned int)f2bf(a1) << 16);
            *reinterpret_cast<unsigned int*>(&abuf[c * 8 + q][d0]) = pk;
        }
    }
    __syncthreads();

    // ---- GEMM2: xres += ao @ W2^T + b2 (N=256, K=256) ----
    {
        short8 afr[8];
        load_afr(afr, &abuf[0][0], AST, 8);
        int n0 = wid * 64;
        for (int nt = 0; nt < 4; nt++) {
            int col = n0 + nt * 16 + (lane & 15);
            const unsigned short* wrow = wb + W2_OFF + (size_t)col * 256 + (lane >> 4) * 8;
            f32x4 acc = {0.f, 0.f, 0.f, 0.f};
            #pragma unroll
            for (int kt = 0; kt < 8; kt++) {
                short8 bfr = *reinterpret_cast<const short8*>(wrow + kt * 32);
                acc = __builtin_amdgcn_mfma_f32_16x16x32_bf16(afr[kt], bfr, acc, 0, 0, 0);
            }
            float bias = out_proj_b[col];
            #pragma unroll
            for (int r = 0; r < 4; r++)
                xres[rb + r][col] += acc[r] + bias;
        }
    }
    __syncthreads();

    // ---- LN2 ----
    do_ln(ln2_w, ln2_b);
    __syncthreads();

    // ---- GEMM3: gff = gelu(h2 @ W3^T + b3) (N=512, K=256) -> qkv buffer ----
    {
        short8 afr[8];
        load_afr(afr, &abuf[0][0], AST, 8);
        int n0 = wid * 128;
        for (int nt = 0; nt < 8; nt++) {
            int col = n0 + nt * 16 + (lane & 15);
            const unsigned short* wrow = wb + W3_OFF + (size_t)col * 256 + (lane >> 4) * 8;
            f32x4 acc = {0.f, 0.f, 0.f, 0.f};
            #pragma unroll
            for (int kt = 0; kt < 8; kt++) {
                short8 bfr = *reinterpret_cast<const short8*>(wrow + kt * 32);
                acc = __builtin_amdgcn_mfma_f32_16x16x32_bf16(afr[kt], bfr, acc, 0, 0, 0);
            }
            float bias = ff1_b[col];
            #pragma unroll
            for (int r = 0; r < 4; r++)
                qkv[rb + r][col] = f2bf(gelu_f(acc[r] + bias));
        }
    }
    __syncthreads();

    // ---- GEMM4: xres += gff @ W4^T + b4 (N=256, K=512) ----
    {
        short8 afr[16];
        load_afr(afr, &qkv[0][0], QST, 16);
        int n0 = wid * 64;
        for (int nt = 0; nt < 4; nt++) {
            int col = n0 + nt * 16 + (lane & 15);
            const unsigned short* wrow = wb + W4_OFF + (size_t)col * 512 + (lane >> 4) * 8;
            f32x4 acc = {0.f, 0.f, 0.f, 0.f};
            #pragma unroll
            for (int kt = 0; kt < 16; kt++) {
                short8 bfr = *reinterpret_cast<const short8*>(wrow + kt * 32);
                acc = __builtin_amdgcn_mfma_f32_16x16x32_bf16(afr[kt], bfr, acc, 0, 0, 0);
            }
            float bias = ff2_b[col];
            #pragma unroll
            for (int r = 0; r < 4; r++)
                xres[rb + r][col] += acc[r] + bias;
        }
    }
    __syncthreads();

    // ---- masked mean pool -> out rows (as feature scratch) ----
    {
        int c  = tid >> 7;
        int d0 = (tid & 127) * 2;
        int m  = s_m[c];
        float p0 = 0.f, p1 = 0.f;
        for (int r = 0; r < m; r++) {
            p0 += xres[c * 8 + r][d0];
            p1 += xres[c * 8 + r][d0 + 1];
        }
        float inv = (m > 0) ? 1.0f / (float)m : 0.0f;
        float2 pv = make_float2(p0 * inv, p1 * inv);
        *reinterpret_cast<float2*>(&out[(size_t)(cg0 + c) * 256 + d0]) = pv;
    }
}

// ===================== head kernel (16 chunks/block, f32) =====================
__global__ __launch_bounds__(256)
void tsa_head(const float* __restrict__ count,
              const float* __restrict__ o1_w, const float* __restrict__ o1_b,
              const float* __restrict__ o2_w, const float* __restrict__ o2_b,
              float* __restrict__ out)   // reads pooled from out rows, overwrites them
{
    __shared__ float feat[16][260];
    __shared__ float g1[16][516];
    const int tid = threadIdx.x;
    const int c0  = blockIdx.x * 16;

    for (int i = tid; i < 16 * 256; i += 256) {
        int c = i >> 8, d = i & 255;
        feat[c][d] = out[(size_t)(c0 + c) * 256 + d];
    }
    if (tid < 16) feat[tid][256] = log1pf(count[c0 + tid]);
    __syncthreads();

    // g1 = gelu(feat @ o1_w^T + o1_b)   (512 outs, 257-dot)
    #pragma unroll
    for (int half = 0; half < 2; half++) {
        int o = half * 256 + tid;
        const float* wr = o1_w + (size_t)o * 257;
        float s[16];
        float b = o1_b[o];
        #pragma unroll
        for (int c = 0; c < 16; c++) s[c] = b;
        for (int d4 = 0; d4 < 64; d4++) {
            float w0 = wr[d4 * 4 + 0], w1 = wr[d4 * 4 + 1];
            float w2 = wr[d4 * 4 + 2], w3 = wr[d4 * 4 + 3];
            #pragma unroll
            for (int c = 0; c < 16; c++) {
                const float* f = &feat[c][d4 * 4];
                s[c] = fmaf(f[3], w3, fmaf(f[2], w2, fmaf(f[1], w1, fmaf(f[0], w0, s[c]))));
            }
        }
        float wl = wr[256];
        #pragma unroll
        for (int c = 0; c < 16; c++)
            g1[c][o] = gelu_f(s[c] + feat[c][256] * wl);
    }
    __syncthreads();

    // out = g1 @ o2_w^T + o2_b   (256 outs, 512-dot)
    {
        int o = tid;
        const float* wr = o2_w + (size_t)o * 512;
        float s[16];
        float b = o2_b[o];
        #pragma unroll
        for (int c = 0; c < 16; c++) s[c] = b;
        for (int d4 = 0; d4 < 128; d4++) {
            float4 w4 = *reinterpret_cast<const float4*>(wr + d4 * 4);
            #pragma unroll
            for (int c = 0; c < 16; c++) {
                const float* g = &g1[c][d4 * 4];
                s[c] = fmaf(g[3], w4.w, fmaf(g[2], w4.z, fmaf(g[1], w4.y, fmaf(g[0], w4.x, s[c]))));
            }
        }
        #pragma unroll
        for (int c = 0; c < 16; c++)
            out[(size_t)(c0 + c) * 256 + o] = s[c];
    }
}

extern "C" void kernel_launch(void* const* d_in, const int* in_sizes, int n_in,
                              void* d_out, int out_size, void* d_ws, size_t ws_size,
                              hipStream_t stream) {
    const float* v          = (const float*)d_in[0];
    const int*   batch_idx  = (const int*)d_in[1];
    const void*  mask       = d_in[2];
    const float* count      = (const float*)d_in[3];
    const float* pos_embed  = (const float*)d_in[4];
    const float* ln1_w      = (const float*)d_in[5];
    const float* ln1_b      = (const float*)d_in[6];
    const float* in_proj_w  = (const float*)d_in[7];
    const float* in_proj_b  = (const float*)d_in[8];
    const float* out_proj_w = (const float*)d_in[9];
    const float* out_proj_b = (const float*)d_in[10];
    const float* ln2_w      = (const float*)d_in[11];
    const float* ln2_b      = (const float*)d_in[12];
    const float* ff1_w      = (const float*)d_in[13];
    const float* ff1_b      = (const float*)d_in[14];
    const float* ff2_w      = (const float*)d_in[15];
    const float* ff2_b      = (const float*)d_in[16];
    const float* o1_w       = (const float*)d_in[17];
    const float* o1_b       = (const float*)d_in[18];
    const float* o2_w       = (const float*)d_in[19];
    const float* o2_b       = (const float*)d_in[20];
    float* out = (float*)d_out;

    unsigned short* wb = (unsigned short*)d_ws;
    int* flag = (int*)((char*)d_ws + (size_t)W_TOTAL * 2);

    conv_weights<<<W_TOTAL / 256, 256, 0, stream>>>(in_proj_w, out_proj_w, ff1_w, ff2_w, wb);
    detect_mask_fmt<<<1, 256, 0, stream>>>((const unsigned int*)mask, 16384, flag);
    tsa_main<<<NCC / G, 256, 0, stream>>>(v, batch_idx, mask, pos_embed,
                                          ln1_w, ln1_b, in_proj_b, out_proj_b,
                                          ln2_w, ln2_b, ff1_b, ff2_b,
                                          wb, flag, out);
    tsa_head<<<NCC / 16, 256, 0, stream>>>(count, o1_w, o1_b, o2_w, o2_b, out);
}

// Round 3
// 731.934 us; speedup vs baseline: 24.4879x; 3.3578x over previous
//
#include <hip/hip_runtime.h>
#include <hip/hip_bf16.h>
#include <math.h>

typedef short short8 __attribute__((ext_vector_type(8)));
typedef float f32x4 __attribute__((ext_vector_type(4)));

#define NCC  32768
#define G    4

// swizzled-weight region offsets in d_ws (units: unsigned short)
#define G1_OFF 0        // in_proj  768x256
#define G2_OFF 196608   // out_proj 256x256
#define G3_OFF 262144   // ff1      512x256
#define G4_OFF 393216   // ff2      256x512
#define O1_OFF 524288   // o1 (first 256 of K=257) 512x256
#define O2_OFF 655360   // o2       256x512
#define SWZ_SHORTS 786432
#define W256_BYTE_OFF (SWZ_SHORTS * 2)
#define FLAG_BYTE_OFF (W256_BYTE_OFF + 2048)

__device__ __forceinline__ float gelu_f(float x) {
    return x * 0.5f * (1.0f + erff(x * 0.70710678118654752f));
}
__device__ __forceinline__ float bf2f(unsigned short u) {
    union { unsigned int i; float f; } w; w.i = ((unsigned int)u) << 16; return w.f;
}
__device__ __forceinline__ unsigned short f2bf(float f) {
    __hip_bfloat16 h = __float2bfloat16(f);
    return *reinterpret_cast<unsigned short*>(&h);
}
// XOR-swizzled index (in shorts) for the 32x256 bf16 A-buffers
__device__ __forceinline__ int aswz(int row, int scol) {
    return (row * 256 + scol) ^ ((row & 7) << 3);
}

// B-frag streamed GEMM core: one ntile, KTS k-steps, 2 M-tiles
template<int KTS>
__device__ __forceinline__ void mfma_nt(const unsigned short* __restrict__ wreg, int fragbase, int lane,
                                        const short8 (&a0)[KTS], const short8 (&a1)[KTS],
                                        f32x4& c0, f32x4& c1) {
    const unsigned short* bp = wreg + (size_t)fragbase * 512 + lane * 8;
    short8 b[KTS];
    #pragma unroll
    for (int kt = 0; kt < KTS; kt++)
        b[kt] = *reinterpret_cast<const short8*>(bp + (size_t)kt * 512);
    #pragma unroll
    for (int kt = 0; kt < KTS; kt++) {
        c0 = __builtin_amdgcn_mfma_f32_16x16x32_bf16(a0[kt], b[kt], c0, 0, 0, 0);
        c1 = __builtin_amdgcn_mfma_f32_16x16x32_bf16(a1[kt], b[kt], c1, 0, 0, 0);
    }
}

// ---- one-time weight swizzle into MFMA B-fragment order ----
__global__ void conv_weights(const float* __restrict__ w1, const float* __restrict__ w2,
                             const float* __restrict__ w3, const float* __restrict__ w4,
                             const float* __restrict__ o1, const float* __restrict__ o2,
                             unsigned short* __restrict__ dst, float* __restrict__ w256) {
    int i = blockIdx.x * 256 + threadIdx.x;
    if (i < 98304) {
        const float* src; int kts, sk, base;
        if (i < 24576)      { src = w1; kts = 8;  sk = 256; base = 0; }
        else if (i < 32768) { src = w2; kts = 8;  sk = 256; base = 24576; }
        else if (i < 49152) { src = w3; kts = 8;  sk = 256; base = 32768; }
        else if (i < 65536) { src = w4; kts = 16; sk = 512; base = 49152; }
        else if (i < 81920) { src = o1; kts = 8;  sk = 257; base = 65536; }
        else                { src = o2; kts = 16; sk = 512; base = 81920; }
        int li   = i - base;
        int lane = li & 63;
        int fi   = li >> 6;
        int kt   = fi % kts;
        int nt   = fi / kts;
        int col  = nt * 16 + (lane & 15);
        int k    = kt * 32 + (lane >> 4) * 8;
        const float* s = src + (size_t)col * sk + k;
        unsigned short* d = dst + (size_t)i * 8;
        #pragma unroll
        for (int e = 0; e < 8; e++) d[e] = f2bf(s[e]);
    } else if (i < 98816) {
        int c = i - 98304;
        w256[c] = o1[(size_t)c * 257 + 256];
    }
}

// ---- mask storage format detect: 0=int32, 1=byte, 2=float32 ----
__global__ void detect_mask_fmt(const unsigned int* __restrict__ mw, int nwords, int* __restrict__ flag) {
    __shared__ int s_bad_int, s_bad_float;
    if (threadIdx.x == 0) { s_bad_int = 0; s_bad_float = 0; }
    __syncthreads();
    int bad_int = 0, bad_float = 0;
    for (int i = threadIdx.x; i < nwords; i += blockDim.x) {
        unsigned int w = mw[i];
        if (w > 1u) bad_int = 1;
        if (w != 0u && w != 0x3F800000u) bad_float = 1;
    }
    if (bad_int)   atomicOr(&s_bad_int, 1);
    if (bad_float) atomicOr(&s_bad_float, 1);
    __syncthreads();
    if (threadIdx.x == 0)
        *flag = (!s_bad_int) ? 0 : ((!s_bad_float) ? 2 : 1);
}

// ===================== main transformer kernel (4 chunks/block, residual in regs) =====================
__global__ __launch_bounds__(256, 2)
void tsa_main(const float* __restrict__ v,
              const int* __restrict__ batch_idx,
              const void* __restrict__ mask,
              const float* __restrict__ pos_embed,
              const float* __restrict__ ln1_w, const float* __restrict__ ln1_b,
              const float* __restrict__ in_proj_b,
              const float* __restrict__ out_proj_b,
              const float* __restrict__ ln2_w, const float* __restrict__ ln2_b,
              const float* __restrict__ ff1_b, const float* __restrict__ ff2_b,
              const unsigned short* __restrict__ wb,
              const int* __restrict__ mask_flag,
              float* __restrict__ out)
{
    __shared__ unsigned short qkbuf[32][520];   // Q|K (512) -> V(0:256) -> gff(0:512)
    __shared__ unsigned short abuf[32 * 256];   // XOR-swizzled A input: ln1 / ao / ln2
    __shared__ unsigned short attwb[G][4][8][8];
    __shared__ float lnred[4][32][2];
    __shared__ int s_idx[G][8];
    __shared__ int s_m[G];
    __shared__ int s_bi[G];

    const int tid  = threadIdx.x;
    const int lane = tid & 63;
    const int wid  = tid >> 6;
    const int cq   = lane >> 4;    // quad group 0..3 -> C-frag row base cq*4
    const int cc   = lane & 15;    // col within 16-tile
    const int cg0  = blockIdx.x * G;

    // residual stream in registers: xr[mt][nt][rr]
    // row = mt*16 + cq*4 + rr ; col = wid*64 + nt*16 + cc
    f32x4 xr[2][4];

    // ---- mask parse (wave w -> chunk w) ----
    {
        int mf = *mask_flag;
        size_t base = (size_t)(cg0 + wid) * 64 + lane;
        int bit;
        if (mf == 0)      bit = ((const int*)mask)[base] != 0;
        else if (mf == 2) bit = ((const float*)mask)[base] != 0.0f;
        else              bit = ((const unsigned char*)mask)[base] != 0;
        unsigned long long bal = __ballot(bit);
        if (lane == 0) {
            int mm = 0; unsigned long long b = bal;
            while (b && mm < 8) { s_idx[wid][mm++] = __ffsll(b) - 1; b &= (b - 1); }
            for (int t = mm; t < 8; t++) s_idx[wid][t] = 0;
            s_m[wid]  = mm;
            s_bi[wid] = batch_idx[cg0 + wid];
        }
    }
    __syncthreads();

    // ---- gather + pos embed -> registers ----
    #pragma unroll
    for (int mt = 0; mt < 2; mt++) {
        int c  = 2 * mt + (cq >> 1);
        int m  = s_m[c];
        int bi = s_bi[c];
        #pragma unroll
        for (int rr = 0; rr < 4; rr++) {
            int rowin = (cq & 1) * 4 + rr;
            int vidx  = s_idx[c][rowin];
            #pragma unroll
            for (int nt = 0; nt < 4; nt++) {
                int col  = wid * 64 + nt * 16 + cc;
                float pe = pos_embed[rowin * 256 + col];
                float val = (rowin < m) ? v[((size_t)bi * 64 + vidx) * 256 + col] : 0.0f;
                xr[mt][nt][rr] = val + pe;
            }
        }
    }

    // ---- layernorm: xr regs -> abuf (bf16, swizzled) ----
    auto do_ln = [&](const float* __restrict__ lw, const float* __restrict__ lb) {
        float sm[2][4], sq[2][4];
        #pragma unroll
        for (int mt = 0; mt < 2; mt++)
            #pragma unroll
            for (int rr = 0; rr < 4; rr++) {
                float s = 0.f, q = 0.f;
                #pragma unroll
                for (int nt = 0; nt < 4; nt++) {
                    float x = xr[mt][nt][rr];
                    s += x; q += x * x;
                }
                sm[mt][rr] = s; sq[mt][rr] = q;
            }
        #pragma unroll
        for (int off = 1; off < 16; off <<= 1) {
            #pragma unroll
            for (int mt = 0; mt < 2; mt++)
                #pragma unroll
                for (int rr = 0; rr < 4; rr++) {
                    sm[mt][rr] += __shfl_xor(sm[mt][rr], off);
                    sq[mt][rr] += __shfl_xor(sq[mt][rr], off);
                }
        }
        if (cc == 0) {
            #pragma unroll
            for (int mt = 0; mt < 2; mt++)
                #pragma unroll
                for (int rr = 0; rr < 4; rr++) {
                    int row = mt * 16 + cq * 4 + rr;
                    lnred[wid][row][0] = sm[mt][rr];
                    lnred[wid][row][1] = sq[mt][rr];
                }
        }
        __syncthreads();
        float mu[2][4], rs[2][4];
        #pragma unroll
        for (int mt = 0; mt < 2; mt++)
            #pragma unroll
            for (int rr = 0; rr < 4; rr++) {
                int row = mt * 16 + cq * 4 + rr;
                float S = 0.f, Q = 0.f;
                #pragma unroll
                for (int w = 0; w < 4; w++) { S += lnred[w][row][0]; Q += lnred[w][row][1]; }
                float m_ = S * (1.0f / 256.0f);
                mu[mt][rr] = m_;
                rs[mt][rr] = rsqrtf(Q * (1.0f / 256.0f) - m_ * m_ + 1e-5f);
            }
        #pragma unroll
        for (int nt = 0; nt < 4; nt++) {
            int col = wid * 64 + nt * 16 + cc;
            float w_ = lw[col], b_ = lb[col];
            #pragma unroll
            for (int mt = 0; mt < 2; mt++)
                #pragma unroll
                for (int rr = 0; rr < 4; rr++) {
                    int row = mt * 16 + cq * 4 + rr;
                    abuf[aswz(row, col)] = f2bf((xr[mt][nt][rr] - mu[mt][rr]) * rs[mt][rr] * w_ + b_);
                }
        }
        __syncthreads();
    };

    auto load_a_swz = [&](short8 (&a0)[8], short8 (&a1)[8]) {
        #pragma unroll
        for (int kt = 0; kt < 8; kt++) {
            a0[kt] = *reinterpret_cast<const short8*>(&abuf[aswz(cc,      kt * 32 + cq * 8)]);
            a1[kt] = *reinterpret_cast<const short8*>(&abuf[aswz(16 + cc, kt * 32 + cq * 8)]);
        }
    };

    // ---- LN1 ----
    do_ln(ln1_w, ln1_b);

    short8 a0[8], a1[8];
    load_a_swz(a0, a1);   // ln1 output; reused for GEMM1a and GEMM1b

    // ---- GEMM1a: Q|K (N=512) ----
    #pragma unroll 2
    for (int nt = 0; nt < 8; nt++) {
        int col = wid * 128 + nt * 16 + cc;
        float b = in_proj_b[col];
        f32x4 c0 = {b, b, b, b}, c1 = {b, b, b, b};
        mfma_nt<8>(wb + G1_OFF, (wid * 8 + nt) * 8, lane, a0, a1, c0, c1);
        #pragma unroll
        for (int r = 0; r < 4; r++) {
            qkbuf[cq * 4 + r][col]      = f2bf(c0[r]);
            qkbuf[16 + cq * 4 + r][col] = f2bf(c1[r]);
        }
    }
    __syncthreads();

    // ---- attention scores + softmax (wave = chunk) ----
    {
        int m  = s_m[wid];
        int qi = lane >> 3, j = lane & 7;
        #pragma unroll
        for (int h = 0; h < 4; h++) {
            const unsigned short* qrow = &qkbuf[wid * 8 + qi][h * 64];
            const unsigned short* krow = &qkbuf[wid * 8 + j][256 + h * 64];
            float s = 0.f;
            #pragma unroll
            for (int d8 = 0; d8 < 8; d8++) {
                short8 qv = *reinterpret_cast<const short8*>(qrow + d8 * 8);
                short8 kv = *reinterpret_cast<const short8*>(krow + d8 * 8);
                #pragma unroll
                for (int t = 0; t < 8; t++)
                    s = fmaf(bf2f((unsigned short)qv[t]), bf2f((unsigned short)kv[t]), s);
            }
            s *= 0.125f;
            if (j >= m) s = -1e30f;
            float mx = s;
            mx = fmaxf(mx, __shfl_xor(mx, 1));
            mx = fmaxf(mx, __shfl_xor(mx, 2));
            mx = fmaxf(mx, __shfl_xor(mx, 4));
            float e = (j < m) ? expf(s - mx) : 0.f;
            float se = e;
            se += __shfl_xor(se, 1);
            se += __shfl_xor(se, 2);
            se += __shfl_xor(se, 4);
            attwb[wid][h][qi][j] = f2bf((se > 0.f) ? e / se : 0.f);
        }
    }
    __syncthreads();

    // ---- GEMM1b: V (N=256) -> qkbuf cols 0..255 (over Q) ----
    #pragma unroll 2
    for (int nt = 0; nt < 4; nt++) {
        int col = wid * 64 + nt * 16 + cc;
        float b = in_proj_b[512 + col];
        f32x4 c0 = {b, b, b, b}, c1 = {b, b, b, b};
        mfma_nt<8>(wb + G1_OFF, (32 + wid * 4 + nt) * 8, lane, a0, a1, c0, c1);
        #pragma unroll
        for (int r = 0; r < 4; r++) {
            qkbuf[cq * 4 + r][col]      = f2bf(c0[r]);
            qkbuf[16 + cq * 4 + r][col] = f2bf(c1[r]);
        }
    }
    __syncthreads();

    // ---- ao = att @ V -> abuf (wave = chunk; lane owns 4 cols) ----
    {
        int h = lane >> 4;
        float vj[8][4];
        #pragma unroll
        for (int j = 0; j < 8; j++) {
            uint2 uv = *reinterpret_cast<const uint2*>(&qkbuf[wid * 8 + j][4 * lane]);
            vj[j][0] = bf2f((unsigned short)(uv.x & 0xffffu));
            vj[j][1] = bf2f((unsigned short)(uv.x >> 16));
            vj[j][2] = bf2f((unsigned short)(uv.y & 0xffffu));
            vj[j][3] = bf2f((unsigned short)(uv.y >> 16));
        }
        #pragma unroll
        for (int q = 0; q < 8; q++) {
            float o0 = 0.f, o1 = 0.f, o2 = 0.f, o3 = 0.f;
            #pragma unroll
            for (int j = 0; j < 8; j++) {
                float aw = bf2f(attwb[wid][h][q][j]);
                o0 = fmaf(aw, vj[j][0], o0);
                o1 = fmaf(aw, vj[j][1], o1);
                o2 = fmaf(aw, vj[j][2], o2);
                o3 = fmaf(aw, vj[j][3], o3);
            }
            unsigned int p0 = (unsigned int)f2bf(o0) | ((unsigned int)f2bf(o1) << 16);
            unsigned int p1 = (unsigned int)f2bf(o2) | ((unsigned int)f2bf(o3) << 16);
            *reinterpret_cast<uint2*>(&abuf[aswz(wid * 8 + q, 4 * lane)]) = make_uint2(p0, p1);
        }
    }
    __syncthreads();

    // ---- GEMM2: xr += ao @ W2^T + b2 ----
    {
        load_a_swz(a0, a1);
        #pragma unroll 2
        for (int nt = 0; nt < 4; nt++) {
            int col = wid * 64 + nt * 16 + cc;
            float b = out_proj_b[col];
            f32x4 c0 = {b, b, b, b}, c1 = {b, b, b, b};
            mfma_nt<8>(wb + G2_OFF, (wid * 4 + nt) * 8, lane, a0, a1, c0, c1);
            xr[0][nt] += c0;
            xr[1][nt] += c1;
        }
    }
    __syncthreads();

    // ---- LN2 ----
    do_ln(ln2_w, ln2_b);

    // ---- GEMM3: gff = gelu(h2 @ W3^T + b3) (N=512) -> qkbuf ----
    {
        load_a_swz(a0, a1);
        #pragma unroll 2
        for (int nt = 0; nt < 8; nt++) {
            int col = wid * 128 + nt * 16 + cc;
            float b = ff1_b[col];
            f32x4 c0 = {b, b, b, b}, c1 = {b, b, b, b};
            mfma_nt<8>(wb + G3_OFF, (wid * 8 + nt) * 8, lane, a0, a1, c0, c1);
            #pragma unroll
            for (int r = 0; r < 4; r++) {
                qkbuf[cq * 4 + r][col]      = f2bf(gelu_f(c0[r]));
                qkbuf[16 + cq * 4 + r][col] = f2bf(gelu_f(c1[r]));
            }
        }
    }
    __syncthreads();

    // ---- GEMM4: xr += gff @ W4^T + b4 (K=512) ----
    {
        f32x4 c[4][2];
        #pragma unroll
        for (int nt = 0; nt < 4; nt++) {
            float b = ff2_b[wid * 64 + nt * 16 + cc];
            c[nt][0] = (f32x4){b, b, b, b};
            c[nt][1] = (f32x4){b, b, b, b};
        }
        #pragma unroll
        for (int half = 0; half < 2; half++) {
            #pragma unroll
            for (int kt = 0; kt < 8; kt++) {
                a0[kt] = *reinterpret_cast<const short8*>(&qkbuf[cc][half * 256 + kt * 32 + cq * 8]);
                a1[kt] = *reinterpret_cast<const short8*>(&qkbuf[16 + cc][half * 256 + kt * 32 + cq * 8]);
            }
            #pragma unroll
            for (int nt = 0; nt < 4; nt++)
                mfma_nt<8>(wb + G4_OFF, (wid * 4 + nt) * 16 + half * 8, lane, a0, a1, c[nt][0], c[nt][1]);
        }
        #pragma unroll
        for (int nt = 0; nt < 4; nt++) {
            xr[0][nt] += c[nt][0];
            xr[1][nt] += c[nt][1];
        }
    }

    // ---- masked mean pool -> out (pooled scratch) ----
    #pragma unroll
    for (int mt = 0; mt < 2; mt++) {
        int c = 2 * mt + (cq >> 1);
        int m = s_m[c];
        float invm = (m > 0) ? 1.0f / (float)m : 0.0f;
        #pragma unroll
        for (int nt = 0; nt < 4; nt++) {
            float p = 0.f;
            #pragma unroll
            for (int rr = 0; rr < 4; rr++)
                if ((cq & 1) * 4 + rr < m) p += xr[mt][nt][rr];
            p += __shfl_xor(p, 16);
            if ((cq & 1) == 0) {
                int col = wid * 64 + nt * 16 + cc;
                out[(size_t)(cg0 + c) * 256 + col] = p * invm;
            }
        }
    }
}

// ===================== head kernel (32 chunks/block, MFMA) =====================
__global__ __launch_bounds__(256, 2)
void tsa_head(const float* __restrict__ count,
              const float* __restrict__ o1_b, const float* __restrict__ o2_b,
              const unsigned short* __restrict__ wb, const float* __restrict__ w256,
              float* __restrict__ out)
{
    __shared__ unsigned short fbuf[32 * 256];   // swizzled feat (bf16)
    __shared__ unsigned short gbuf[32][520];    // g1 (bf16)
    __shared__ float cbuf[32];

    const int tid  = threadIdx.x;
    const int lane = tid & 63;
    const int wid  = tid >> 6;
    const int cq   = lane >> 4;
    const int cc   = lane & 15;
    const int c0b  = blockIdx.x * 32;

    for (int i = tid; i < 32 * 256; i += 256) {
        int row = i >> 8, col = i & 255;
        fbuf[aswz(row, col)] = f2bf(out[(size_t)(c0b + row) * 256 + col]);
    }
    if (tid < 32) cbuf[tid] = log1pf(count[c0b + tid]);
    __syncthreads();

    short8 a0[8], a1[8];
    #pragma unroll
    for (int kt = 0; kt < 8; kt++) {
        a0[kt] = *reinterpret_cast<const short8*>(&fbuf[aswz(cc,      kt * 32 + cq * 8)]);
        a1[kt] = *reinterpret_cast<const short8*>(&fbuf[aswz(16 + cc, kt * 32 + cq * 8)]);
    }

    // ---- o1: g1 = gelu(feat @ o1_w^T + cnt*w256 + b) ----
    #pragma unroll 2
    for (int nt = 0; nt < 8; nt++) {
        int col  = wid * 128 + nt * 16 + cc;
        float b  = o1_b[col];
        float wc = w256[col];
        f32x4 c0 = {b, b, b, b}, c1 = {b, b, b, b};
        mfma_nt<8>(wb + O1_OFF, (wid * 8 + nt) * 8, lane, a0, a1, c0, c1);
        #pragma unroll
        for (int r = 0; r < 4; r++) {
            int r0 = cq * 4 + r, r1 = 16 + cq * 4 + r;
            gbuf[r0][col] = f2bf(gelu_f(c0[r] + cbuf[r0] * wc));
            gbuf[r1][col] = f2bf(gelu_f(c1[r] + cbuf[r1] * wc));
        }
    }
    __syncthreads();

    // ---- o2: out = g1 @ o2_w^T + b (K=512) ----
    {
        f32x4 c[4][2];
        #pragma unroll
        for (int nt = 0; nt < 4; nt++) {
            float b = o2_b[wid * 64 + nt * 16 + cc];
            c[nt][0] = (f32x4){b, b, b, b};
            c[nt][1] = (f32x4){b, b, b, b};
        }
        #pragma unroll
        for (int half = 0; half < 2; half++) {
            #pragma unroll
            for (int kt = 0; kt < 8; kt++) {
                a0[kt] = *reinterpret_cast<const short8*>(&gbuf[cc][half * 256 + kt * 32 + cq * 8]);
                a1[kt] = *reinterpret_cast<const short8*>(&gbuf[16 + cc][half * 256 + kt * 32 + cq * 8]);
            }
            #pragma unroll
            for (int nt = 0; nt < 4; nt++)
                mfma_nt<8>(wb + O2_OFF, (wid * 4 + nt) * 16 + half * 8, lane, a0, a1, c[nt][0], c[nt][1]);
        }
        #pragma unroll
        for (int nt = 0; nt < 4; nt++) {
            int col = wid * 64 + nt * 16 + cc;
            #pragma unroll
            for (int r = 0; r < 4; r++) {
                out[(size_t)(c0b + cq * 4 + r) * 256 + col]      = c[nt][0][r];
                out[(size_t)(c0b + 16 + cq * 4 + r) * 256 + col] = c[nt][1][r];
            }
        }
    }
}

extern "C" void kernel_launch(void* const* d_in, const int* in_sizes, int n_in,
                              void* d_out, int out_size, void* d_ws, size_t ws_size,
                              hipStream_t stream) {
    const float* v          = (const float*)d_in[0];
    const int*   batch_idx  = (const int*)d_in[1];
    const void*  mask       = d_in[2];
    const float* count      = (const float*)d_in[3];
    const float* pos_embed  = (const float*)d_in[4];
    const float* ln1_w      = (const float*)d_in[5];
    const float* ln1_b      = (const float*)d_in[6];
    const float* in_proj_w  = (const float*)d_in[7];
    const float* in_proj_b  = (const float*)d_in[8];
    const float* out_proj_w = (const float*)d_in[9];
    const float* out_proj_b = (const float*)d_in[10];
    const float* ln2_w      = (const float*)d_in[11];
    const float* ln2_b      = (const float*)d_in[12];
    const float* ff1_w      = (const float*)d_in[13];
    const float* ff1_b      = (const float*)d_in[14];
    const float* ff2_w      = (const float*)d_in[15];
    const float* ff2_b      = (const float*)d_in[16];
    const float* o1_w       = (const float*)d_in[17];
    const float* o1_b       = (const float*)d_in[18];
    const float* o2_w       = (const float*)d_in[19];
    const float* o2_b       = (const float*)d_in[20];
    float* out = (float*)d_out;

    unsigned short* wb = (unsigned short*)d_ws;
    float* w256 = (float*)((char*)d_ws + W256_BYTE_OFF);
    int* flag   = (int*)((char*)d_ws + FLAG_BYTE_OFF);

    conv_weights<<<387, 256, 0, stream>>>(in_proj_w, out_proj_w, ff1_w, ff2_w, o1_w, o2_w, wb, w256);
    detect_mask_fmt<<<1, 256, 0, stream>>>((const unsigned int*)mask, 16384, flag);
    tsa_main<<<NCC / G, 256, 0, stream>>>(v, batch_idx, mask, pos_embed,
                                          ln1_w, ln1_b, in_proj_b, out_proj_b,
                                          ln2_w, ln2_b, ff1_b, ff2_b,
                                          wb, flag, out);
    tsa_head<<<NCC / 32, 256, 0, stream>>>(count, o1_b, o2_b, wb, w256, out);
}

// Round 4
// 613.895 us; speedup vs baseline: 29.1964x; 1.1923x over previous
//
#include <hip/hip_runtime.h>
#include <hip/hip_bf16.h>
#include <math.h>

typedef short short8 __attribute__((ext_vector_type(8)));
typedef short short4v __attribute__((ext_vector_type(4)));
typedef float f32x4 __attribute__((ext_vector_type(4)));

#define NCC  32768
#define G    4
#define QST  520    // qkbuf stride (shorts)

// swizzled-weight region offsets in d_ws (units: unsigned short)
#define G1_OFF 0        // in_proj  768x256
#define G2_OFF 196608   // out_proj 256x256
#define G3_OFF 262144   // ff1      512x256
#define G4_OFF 393216   // ff2      256x512
#define O1_OFF 524288   // o1 (first 256 of K=257) 512x256
#define O2_OFF 655360   // o2       256x512
#define SWZ_SHORTS 786432
#define W256_BYTE_OFF (SWZ_SHORTS * 2)
#define FLAG_BYTE_OFF (W256_BYTE_OFF + 2048)

__device__ __forceinline__ float gelu_f(float x) {
    return x * 0.5f * (1.0f + erff(x * 0.70710678118654752f));
}
__device__ __forceinline__ float bf2f(unsigned short u) {
    union { unsigned int i; float f; } w; w.i = ((unsigned int)u) << 16; return w.f;
}
__device__ __forceinline__ unsigned short f2bf(float f) {
    __hip_bfloat16 h = __float2bfloat16(f);
    return *reinterpret_cast<unsigned short*>(&h);
}
// XOR-swizzled index (in shorts) for 32x256 bf16 A-layout buffers
__device__ __forceinline__ int aswz(int row, int scol) {
    return (row * 256 + scol) ^ ((row & 7) << 3);
}
// Vt swizzle: Vt[d][j], d<256, j<32
__device__ __forceinline__ int vtswz(int d, int j) {
    return d * 32 + (j ^ ((d & 7) << 2));
}

template<int KTS>
__device__ __forceinline__ void load_bgrp(short8 (&b)[KTS], const unsigned short* __restrict__ base) {
    #pragma unroll
    for (int kt = 0; kt < KTS; kt++)
        b[kt] = *reinterpret_cast<const short8*>(base + (size_t)kt * 512);
}

// ---- one-time weight swizzle into MFMA B-fragment order ----
__global__ void conv_weights(const float* __restrict__ w1, const float* __restrict__ w2,
                             const float* __restrict__ w3, const float* __restrict__ w4,
                             const float* __restrict__ o1, const float* __restrict__ o2,
                             unsigned short* __restrict__ dst, float* __restrict__ w256) {
    int i = blockIdx.x * 256 + threadIdx.x;
    if (i < 98304) {
        const float* src; int kts, sk, base;
        if (i < 24576)      { src = w1; kts = 8;  sk = 256; base = 0; }
        else if (i < 32768) { src = w2; kts = 8;  sk = 256; base = 24576; }
        else if (i < 49152) { src = w3; kts = 8;  sk = 256; base = 32768; }
        else if (i < 65536) { src = w4; kts = 16; sk = 512; base = 49152; }
        else if (i < 81920) { src = o1; kts = 8;  sk = 257; base = 65536; }
        else                { src = o2; kts = 16; sk = 512; base = 81920; }
        int li   = i - base;
        int lane = li & 63;
        int fi   = li >> 6;
        int kt   = fi % kts;
        int nt   = fi / kts;
        int col  = nt * 16 + (lane & 15);
        int k    = kt * 32 + (lane >> 4) * 8;
        const float* s = src + (size_t)col * sk + k;
        unsigned short* d = dst + (size_t)i * 8;
        #pragma unroll
        for (int e = 0; e < 8; e++) d[e] = f2bf(s[e]);
    } else if (i < 98816) {
        int c = i - 98304;
        w256[c] = o1[(size_t)c * 257 + 256];
    }
}

// ---- mask storage format detect: 0=int32, 1=byte, 2=float32 ----
__global__ void detect_mask_fmt(const unsigned int* __restrict__ mw, int nwords, int* __restrict__ flag) {
    __shared__ int s_bad_int, s_bad_float;
    if (threadIdx.x == 0) { s_bad_int = 0; s_bad_float = 0; }
    __syncthreads();
    int bad_int = 0, bad_float = 0;
    for (int i = threadIdx.x; i < nwords; i += blockDim.x) {
        unsigned int w = mw[i];
        if (w > 1u) bad_int = 1;
        if (w != 0u && w != 0x3F800000u) bad_float = 1;
    }
    if (bad_int)   atomicOr(&s_bad_int, 1);
    if (bad_float) atomicOr(&s_bad_float, 1);
    __syncthreads();
    if (threadIdx.x == 0)
        *flag = (!s_bad_int) ? 0 : ((!s_bad_float) ? 2 : 1);
}

// ===================== main transformer kernel =====================
__global__ __launch_bounds__(256, 2)
void tsa_main(const float* __restrict__ v,
              const int* __restrict__ batch_idx,
              const void* __restrict__ mask,
              const float* __restrict__ pos_embed,
              const float* __restrict__ ln1_w, const float* __restrict__ ln1_b,
              const float* __restrict__ in_proj_b,
              const float* __restrict__ out_proj_b,
              const float* __restrict__ ln2_w, const float* __restrict__ ln2_b,
              const float* __restrict__ ff1_b, const float* __restrict__ ff2_b,
              const unsigned short* __restrict__ wb,
              const int* __restrict__ mask_flag,
              float* __restrict__ out)
{
    __shared__ unsigned short qkbuf[32 * QST];      // Q|K -> ao(swz) -> gff
    __shared__ unsigned short abuf[32 * 256];       // LN1(swz) -> Vt(swz) -> LN2(swz)
    __shared__ unsigned short attw_s[2][4][16][16]; // P (bf16); overlaid by lnred during LN
    __shared__ int s_idx[G][8];
    __shared__ int s_m[G];
    __shared__ int s_bi[G];

    float (*lnred)[32][2] = reinterpret_cast<float (*)[32][2]>(&attw_s[0][0][0][0]);

    const int tid  = threadIdx.x;
    const int lane = tid & 63;
    const int wid  = tid >> 6;
    const int cq   = lane >> 4;
    const int cc   = lane & 15;
    const int cg0  = blockIdx.x * G;
    const int pair = wid >> 1;

    f32x4 xr[2][4];   // residual: row = mt*16+cq*4+r, col = wid*64+nt*16+cc

    // ---- mask parse (wave w -> chunk w) ----
    {
        int mf = *mask_flag;
        size_t base = (size_t)(cg0 + wid) * 64 + lane;
        int bit;
        if (mf == 0)      bit = ((const int*)mask)[base] != 0;
        else if (mf == 2) bit = ((const float*)mask)[base] != 0.0f;
        else              bit = ((const unsigned char*)mask)[base] != 0;
        unsigned long long bal = __ballot(bit);
        if (lane == 0) {
            int mm = 0; unsigned long long b = bal;
            while (b && mm < 8) { s_idx[wid][mm++] = __ffsll(b) - 1; b &= (b - 1); }
            for (int t = mm; t < 8; t++) s_idx[wid][t] = 0;
            s_m[wid]  = mm;
            s_bi[wid] = batch_idx[cg0 + wid];
        }
    }
    __syncthreads();

    // ---- gather + pos embed -> registers ----
    #pragma unroll
    for (int mt = 0; mt < 2; mt++) {
        int c  = 2 * mt + (cq >> 1);
        int m  = s_m[c];
        int bi = s_bi[c];
        #pragma unroll
        for (int rr = 0; rr < 4; rr++) {
            int rowin = (cq & 1) * 4 + rr;
            int vidx  = s_idx[c][rowin];
            #pragma unroll
            for (int nt = 0; nt < 4; nt++) {
                int col  = wid * 64 + nt * 16 + cc;
                float pe = pos_embed[rowin * 256 + col];
                float val = (rowin < m) ? v[((size_t)bi * 64 + vidx) * 256 + col] : 0.0f;
                xr[mt][nt][rr] = val + pe;
            }
        }
    }

    // ---- layernorm: xr regs -> abuf (bf16, swizzled) ----
    auto do_ln = [&](const float* __restrict__ lw, const float* __restrict__ lb) {
        float sm[2][4], sq[2][4];
        #pragma unroll
        for (int mt = 0; mt < 2; mt++)
            #pragma unroll
            for (int rr = 0; rr < 4; rr++) {
                float s = 0.f, q = 0.f;
                #pragma unroll
                for (int nt = 0; nt < 4; nt++) {
                    float x = xr[mt][nt][rr];
                    s += x; q += x * x;
                }
                sm[mt][rr] = s; sq[mt][rr] = q;
            }
        #pragma unroll
        for (int off = 1; off < 16; off <<= 1) {
            #pragma unroll
            for (int mt = 0; mt < 2; mt++)
                #pragma unroll
                for (int rr = 0; rr < 4; rr++) {
                    sm[mt][rr] += __shfl_xor(sm[mt][rr], off);
                    sq[mt][rr] += __shfl_xor(sq[mt][rr], off);
                }
        }
        __syncthreads();   // protect lnred region (attw) from previous phase
        if (cc == 0) {
            #pragma unroll
            for (int mt = 0; mt < 2; mt++)
                #pragma unroll
                for (int rr = 0; rr < 4; rr++) {
                    int row = mt * 16 + cq * 4 + rr;
                    lnred[wid][row][0] = sm[mt][rr];
                    lnred[wid][row][1] = sq[mt][rr];
                }
        }
        __syncthreads();
        float mu[2][4], rs[2][4];
        #pragma unroll
        for (int mt = 0; mt < 2; mt++)
            #pragma unroll
            for (int rr = 0; rr < 4; rr++) {
                int row = mt * 16 + cq * 4 + rr;
                float S = 0.f, Q = 0.f;
                #pragma unroll
                for (int w = 0; w < 4; w++) { S += lnred[w][row][0]; Q += lnred[w][row][1]; }
                float m_ = S * (1.0f / 256.0f);
                mu[mt][rr] = m_;
                rs[mt][rr] = rsqrtf(Q * (1.0f / 256.0f) - m_ * m_ + 1e-5f);
            }
        #pragma unroll
        for (int nt = 0; nt < 4; nt++) {
            int col = wid * 64 + nt * 16 + cc;
            float w_ = lw[col], b_ = lb[col];
            #pragma unroll
            for (int mt = 0; mt < 2; mt++)
                #pragma unroll
                for (int rr = 0; rr < 4; rr++) {
                    int row = mt * 16 + cq * 4 + rr;
                    abuf[aswz(row, col)] = f2bf((xr[mt][nt][rr] - mu[mt][rr]) * rs[mt][rr] * w_ + b_);
                }
        }
        __syncthreads();
    };

    auto load_a_from = [&](short8 (&a0)[8], short8 (&a1)[8], const unsigned short* base) {
        #pragma unroll
        for (int kt = 0; kt < 8; kt++) {
            a0[kt] = *reinterpret_cast<const short8*>(&base[aswz(cc,      kt * 32 + cq * 8)]);
            a1[kt] = *reinterpret_cast<const short8*>(&base[aswz(16 + cc, kt * 32 + cq * 8)]);
        }
    };

    // ---- LN1 ----
    do_ln(ln1_w, ln1_b);

    // ---- GEMM1 (merged QKV, NT=12, B double-buffered) ----
    {
        short8 a0[8], a1[8];
        load_a_from(a0, a1, abuf);
        __syncthreads();   // all a-frags loaded before Vt overwrites abuf

        auto bbase = [&](int nt) {
            int gnt = (nt < 8) ? (wid * 8 + nt) : (32 + wid * 4 + (nt - 8));
            return wb + G1_OFF + (size_t)gnt * 8 * 512 + lane * 8;
        };
        short8 bb[2][8];
        load_bgrp<8>(bb[0], bbase(0));
        #pragma unroll
        for (int nt = 0; nt < 12; nt++) {
            if (nt + 1 < 12) load_bgrp<8>(bb[(nt + 1) & 1], bbase(nt + 1));
            float b = (nt < 8) ? in_proj_b[wid * 128 + nt * 16 + cc]
                               : in_proj_b[512 + wid * 64 + (nt - 8) * 16 + cc];
            f32x4 c0 = {b, b, b, b}, c1 = {b, b, b, b};
            #pragma unroll
            for (int kt = 0; kt < 8; kt++) {
                c0 = __builtin_amdgcn_mfma_f32_16x16x32_bf16(a0[kt], bb[nt & 1][kt], c0, 0, 0, 0);
                c1 = __builtin_amdgcn_mfma_f32_16x16x32_bf16(a1[kt], bb[nt & 1][kt], c1, 0, 0, 0);
            }
            if (nt < 8) {
                int col = wid * 128 + nt * 16 + cc;
                #pragma unroll
                for (int r = 0; r < 4; r++) {
                    qkbuf[(cq * 4 + r) * QST + col]      = f2bf(c0[r]);
                    qkbuf[(16 + cq * 4 + r) * QST + col] = f2bf(c1[r]);
                }
            } else {
                int d = wid * 64 + (nt - 8) * 16 + cc;
                short4v p0, p1;
                #pragma unroll
                for (int r = 0; r < 4; r++) { p0[r] = (short)f2bf(c0[r]); p1[r] = (short)f2bf(c1[r]); }
                *reinterpret_cast<short4v*>(&abuf[vtswz(d, cq * 4)])      = p0;
                *reinterpret_cast<short4v*>(&abuf[vtswz(d, 16 + cq * 4)]) = p1;
            }
        }
    }
    __syncthreads();

    // ---- attention scores (MFMA) + softmax -> P ----
    {
        #pragma unroll
        for (int hj = 0; hj < 2; hj++) {
            int h = (wid & 1) * 2 + hj;
            f32x4 c = {0.f, 0.f, 0.f, 0.f};
            #pragma unroll
            for (int kt = 0; kt < 2; kt++) {
                short8 qa = *reinterpret_cast<const short8*>(&qkbuf[(pair * 16 + cc) * QST + h * 64 + cq * 8 + kt * 32]);
                short8 kb = *reinterpret_cast<const short8*>(&qkbuf[(pair * 16 + cc) * QST + 256 + h * 64 + cq * 8 + kt * 32]);
                c = __builtin_amdgcn_mfma_f32_16x16x32_bf16(qa, kb, c, 0, 0, 0);
            }
            int jhalf = cc >> 3, jloc = cc & 7;
            #pragma unroll
            for (int r = 0; r < 4; r++) {
                int q = cq * 4 + r;
                int qhalf = q >> 3;
                int m = s_m[pair * 2 + qhalf];
                bool valid = (jhalf == qhalf) && (jloc < m);
                float s = valid ? c[r] * 0.125f : -1e30f;
                float mx = s;
                mx = fmaxf(mx, __shfl_xor(mx, 1));
                mx = fmaxf(mx, __shfl_xor(mx, 2));
                mx = fmaxf(mx, __shfl_xor(mx, 4));
                float e = valid ? __expf(s - mx) : 0.f;
                float se = e;
                se += __shfl_xor(se, 1);
                se += __shfl_xor(se, 2);
                se += __shfl_xor(se, 4);
                attw_s[pair][h][q][cc] = f2bf((se > 0.f) ? e / se : 0.f);
            }
        }
    }
    __syncthreads();

    // ---- PV (MFMA, K=32 zero-padded) -> ao (swizzled into qkbuf) ----
    {
        int jbg = pair * 16 + (cq & 1) * 8;
        #pragma unroll
        for (int hj = 0; hj < 2; hj++) {
            int h = (wid & 1) * 2 + hj;
            short8 pa;
            if (cq < 2) pa = *reinterpret_cast<const short8*>(&attw_s[pair][h][cc][cq * 8]);
            else        pa = (short8)((short)0);
            #pragma unroll
            for (int t = 0; t < 4; t++) {
                int d = h * 64 + t * 16 + cc;
                short4v lo = *reinterpret_cast<const short4v*>(&abuf[vtswz(d, jbg)]);
                short4v hi = *reinterpret_cast<const short4v*>(&abuf[vtswz(d, jbg + 4)]);
                union { short8 v; short4v half2[2]; } u;
                u.half2[0] = lo; u.half2[1] = hi;
                f32x4 c = {0.f, 0.f, 0.f, 0.f};
                c = __builtin_amdgcn_mfma_f32_16x16x32_bf16(pa, u.v, c, 0, 0, 0);
                #pragma unroll
                for (int r = 0; r < 4; r++)
                    qkbuf[aswz(pair * 16 + cq * 4 + r, d)] = f2bf(c[r]);
            }
        }
    }
    __syncthreads();

    // ---- GEMM2: xr += ao @ W2^T + b2 (NT=4, dbuf) ----
    {
        short8 a0[8], a1[8];
        load_a_from(a0, a1, qkbuf);
        short8 bb[2][8];
        auto bbase = [&](int nt) {
            return wb + G2_OFF + (size_t)(wid * 4 + nt) * 8 * 512 + lane * 8;
        };
        load_bgrp<8>(bb[0], bbase(0));
        #pragma unroll
        for (int nt = 0; nt < 4; nt++) {
            if (nt + 1 < 4) load_bgrp<8>(bb[(nt + 1) & 1], bbase(nt + 1));
            float b = out_proj_b[wid * 64 + nt * 16 + cc];
            f32x4 c0 = {b, b, b, b}, c1 = {b, b, b, b};
            #pragma unroll
            for (int kt = 0; kt < 8; kt++) {
                c0 = __builtin_amdgcn_mfma_f32_16x16x32_bf16(a0[kt], bb[nt & 1][kt], c0, 0, 0, 0);
                c1 = __builtin_amdgcn_mfma_f32_16x16x32_bf16(a1[kt], bb[nt & 1][kt], c1, 0, 0, 0);
            }
            xr[0][nt] += c0;
            xr[1][nt] += c1;
        }
    }
    __syncthreads();

    // ---- LN2 ----
    do_ln(ln2_w, ln2_b);

    // ---- GEMM3: gff = gelu(h2 @ W3^T + b3) (NT=8, dbuf) -> qkbuf ----
    {
        short8 a0[8], a1[8];
        load_a_from(a0, a1, abuf);
        short8 bb[2][8];
        auto bbase = [&](int nt) {
            return wb + G3_OFF + (size_t)(wid * 8 + nt) * 8 * 512 + lane * 8;
        };
        load_bgrp<8>(bb[0], bbase(0));
        #pragma unroll
        for (int nt = 0; nt < 8; nt++) {
            if (nt + 1 < 8) load_bgrp<8>(bb[(nt + 1) & 1], bbase(nt + 1));
            float b = ff1_b[wid * 128 + nt * 16 + cc];
            f32x4 c0 = {b, b, b, b}, c1 = {b, b, b, b};
            #pragma unroll
            for (int kt = 0; kt < 8; kt++) {
                c0 = __builtin_amdgcn_mfma_f32_16x16x32_bf16(a0[kt], bb[nt & 1][kt], c0, 0, 0, 0);
                c1 = __builtin_amdgcn_mfma_f32_16x16x32_bf16(a1[kt], bb[nt & 1][kt], c1, 0, 0, 0);
            }
            int col = wid * 128 + nt * 16 + cc;
            #pragma unroll
            for (int r = 0; r < 4; r++) {
                qkbuf[(cq * 4 + r) * QST + col]      = f2bf(gelu_f(c0[r]));
                qkbuf[(16 + cq * 4 + r) * QST + col] = f2bf(gelu_f(c1[r]));
            }
        }
    }
    __syncthreads();

    // ---- GEMM4: xr += gff @ W4^T + b4 (K=512, two halves, dbuf) ----
    {
        f32x4 c[4][2];
        #pragma unroll
        for (int nt = 0; nt < 4; nt++) {
            float b = ff2_b[wid * 64 + nt * 16 + cc];
            c[nt][0] = (f32x4){b, b, b, b};
            c[nt][1] = (f32x4){b, b, b, b};
        }
        #pragma unroll
        for (int half = 0; half < 2; half++) {
            short8 a0[8], a1[8];
            #pragma unroll
            for (int kt = 0; kt < 8; kt++) {
                a0[kt] = *reinterpret_cast<const short8*>(&qkbuf[cc * QST        + half * 256 + kt * 32 + cq * 8]);
                a1[kt] = *reinterpret_cast<const short8*>(&qkbuf[(16 + cc) * QST + half * 256 + kt * 32 + cq * 8]);
            }
            short8 bb[2][8];
            auto bbase = [&](int nt) {
                return wb + G4_OFF + (size_t)((wid * 4 + nt) * 16 + half * 8) * 512 + lane * 8;
            };
            load_bgrp<8>(bb[0], bbase(0));
            #pragma unroll
            for (int nt = 0; nt < 4; nt++) {
                if (nt + 1 < 4) load_bgrp<8>(bb[(nt + 1) & 1], bbase(nt + 1));
                #pragma unroll
                for (int kt = 0; kt < 8; kt++) {
                    c[nt][0] = __builtin_amdgcn_mfma_f32_16x16x32_bf16(a0[kt], bb[nt & 1][kt], c[nt][0], 0, 0, 0);
                    c[nt][1] = __builtin_amdgcn_mfma_f32_16x16x32_bf16(a1[kt], bb[nt & 1][kt], c[nt][1], 0, 0, 0);
                }
            }
        }
        #pragma unroll
        for (int nt = 0; nt < 4; nt++) {
            xr[0][nt] += c[nt][0];
            xr[1][nt] += c[nt][1];
        }
    }

    // ---- masked mean pool -> out (pooled scratch) ----
    #pragma unroll
    for (int mt = 0; mt < 2; mt++) {
        int c = 2 * mt + (cq >> 1);
        int m = s_m[c];
        float invm = (m > 0) ? 1.0f / (float)m : 0.0f;
        #pragma unroll
        for (int nt = 0; nt < 4; nt++) {
            float p = 0.f;
            #pragma unroll
            for (int rr = 0; rr < 4; rr++)
                if ((cq & 1) * 4 + rr < m) p += xr[mt][nt][rr];
            p += __shfl_xor(p, 16);
            if ((cq & 1) == 0) {
                int col = wid * 64 + nt * 16 + cc;
                out[(size_t)(cg0 + c) * 256 + col] = p * invm;
            }
        }
    }
}

// ===================== head kernel (32 chunks/block, MFMA) =====================
__global__ __launch_bounds__(256, 2)
void tsa_head(const float* __restrict__ count,
              const float* __restrict__ o1_b, const float* __restrict__ o2_b,
              const unsigned short* __restrict__ wb, const float* __restrict__ w256,
              float* __restrict__ out)
{
    __shared__ unsigned short fbuf[32 * 256];
    __shared__ unsigned short gbuf[32][520];
    __shared__ float cbuf[32];

    const int tid  = threadIdx.x;
    const int lane = tid & 63;
    const int wid  = tid >> 6;
    const int cq   = lane >> 4;
    const int cc   = lane & 15;
    const int c0b  = blockIdx.x * 32;

    for (int i = tid; i < 32 * 256; i += 256) {
        int row = i >> 8, col = i & 255;
        fbuf[aswz(row, col)] = f2bf(out[(size_t)(c0b + row) * 256 + col]);
    }
    if (tid < 32) cbuf[tid] = log1pf(count[c0b + tid]);
    __syncthreads();

    short8 a0[8], a1[8];
    #pragma unroll
    for (int kt = 0; kt < 8; kt++) {
        a0[kt] = *reinterpret_cast<const short8*>(&fbuf[aswz(cc,      kt * 32 + cq * 8)]);
        a1[kt] = *reinterpret_cast<const short8*>(&fbuf[aswz(16 + cc, kt * 32 + cq * 8)]);
    }

    // ---- o1: g1 = gelu(feat @ o1_w^T + cnt*w256 + b) ----
    {
        short8 bb[2][8];
        auto bbase = [&](int nt) {
            return wb + O1_OFF + (size_t)(wid * 8 + nt) * 8 * 512 + lane * 8;
        };
        load_bgrp<8>(bb[0], bbase(0));
        #pragma unroll
        for (int nt = 0; nt < 8; nt++) {
            if (nt + 1 < 8) load_bgrp<8>(bb[(nt + 1) & 1], bbase(nt + 1));
            int col  = wid * 128 + nt * 16 + cc;
            float b  = o1_b[col];
            float wc = w256[col];
            f32x4 c0 = {b, b, b, b}, c1 = {b, b, b, b};
            #pragma unroll
            for (int kt = 0; kt < 8; kt++) {
                c0 = __builtin_amdgcn_mfma_f32_16x16x32_bf16(a0[kt], bb[nt & 1][kt], c0, 0, 0, 0);
                c1 = __builtin_amdgcn_mfma_f32_16x16x32_bf16(a1[kt], bb[nt & 1][kt], c1, 0, 0, 0);
            }
            #pragma unroll
            for (int r = 0; r < 4; r++) {
                int r0 = cq * 4 + r, r1 = 16 + cq * 4 + r;
                gbuf[r0][col] = f2bf(gelu_f(c0[r] + cbuf[r0] * wc));
                gbuf[r1][col] = f2bf(gelu_f(c1[r] + cbuf[r1] * wc));
            }
        }
    }
    __syncthreads();

    // ---- o2: out = g1 @ o2_w^T + b (K=512) ----
    {
        f32x4 c[4][2];
        #pragma unroll
        for (int nt = 0; nt < 4; nt++) {
            float b = o2_b[wid * 64 + nt * 16 + cc];
            c[nt][0] = (f32x4){b, b, b, b};
            c[nt][1] = (f32x4){b, b, b, b};
        }
        #pragma unroll
        for (int half = 0; half < 2; half++) {
            #pragma unroll
            for (int kt = 0; kt < 8; kt++) {
                a0[kt] = *reinterpret_cast<const short8*>(&gbuf[cc][half * 256 + kt * 32 + cq * 8]);
                a1[kt] = *reinterpret_cast<const short8*>(&gbuf[16 + cc][half * 256 + kt * 32 + cq * 8]);
            }
            short8 bb[2][8];
            auto bbase = [&](int nt) {
                return wb + O2_OFF + (size_t)((wid * 4 + nt) * 16 + half * 8) * 512 + lane * 8;
            };
            load_bgrp<8>(bb[0], bbase(0));
            #pragma unroll
            for (int nt = 0; nt < 4; nt++) {
                if (nt + 1 < 4) load_bgrp<8>(bb[(nt + 1) & 1], bbase(nt + 1));
                #pragma unroll
                for (int kt = 0; kt < 8; kt++) {
                    c[nt][0] = __builtin_amdgcn_mfma_f32_16x16x32_bf16(a0[kt], bb[nt & 1][kt], c[nt][0], 0, 0, 0);
                    c[nt][1] = __builtin_amdgcn_mfma_f32_16x16x32_bf16(a1[kt], bb[nt & 1][kt], c[nt][1], 0, 0, 0);
                }
            }
        }
        #pragma unroll
        for (int nt = 0; nt < 4; nt++) {
            int col = wid * 64 + nt * 16 + cc;
            #pragma unroll
            for (int r = 0; r < 4; r++) {
                out[(size_t)(c0b + cq * 4 + r) * 256 + col]      = c[nt][0][r];
                out[(size_t)(c0b + 16 + cq * 4 + r) * 256 + col] = c[nt][1][r];
            }
        }
    }
}

extern "C" void kernel_launch(void* const* d_in, const int* in_sizes, int n_in,
                              void* d_out, int out_size, void* d_ws, size_t ws_size,
                              hipStream_t stream) {
    const float* v          = (const float*)d_in[0];
    const int*   batch_idx  = (const int*)d_in[1];
    const void*  mask       = d_in[2];
    const float* count      = (const float*)d_in[3];
    const float* pos_embed  = (const float*)d_in[4];
    const float* ln1_w      = (const float*)d_in[5];
    const float* ln1_b      = (const float*)d_in[6];
    const float* in_proj_w  = (const float*)d_in[7];
    const float* in_proj_b  = (const float*)d_in[8];
    const float* out_proj_w = (const float*)d_in[9];
    const float* out_proj_b = (const float*)d_in[10];
    const float* ln2_w      = (const float*)d_in[11];
    const float* ln2_b      = (const float*)d_in[12];
    const float* ff1_w      = (const float*)d_in[13];
    const float* ff1_b      = (const float*)d_in[14];
    const float* ff2_w      = (const float*)d_in[15];
    const float* ff2_b      = (const float*)d_in[16];
    const float* o1_w       = (const float*)d_in[17];
    const float* o1_b       = (const float*)d_in[18];
    const float* o2_w       = (const float*)d_in[19];
    const float* o2_b       = (const float*)d_in[20];
    float* out = (float*)d_out;

    unsigned short* wb = (unsigned short*)d_ws;
    float* w256 = (float*)((char*)d_ws + W256_BYTE_OFF);
    int* flag   = (int*)((char*)d_ws + FLAG_BYTE_OFF);

    conv_weights<<<387, 256, 0, stream>>>(in_proj_w, out_proj_w, ff1_w, ff2_w, o1_w, o2_w, wb, w256);
    detect_mask_fmt<<<1, 256, 0, stream>>>((const unsigned int*)mask, 16384, flag);
    tsa_main<<<NCC / G, 256, 0, stream>>>(v, batch_idx, mask, pos_embed,
                                          ln1_w, ln1_b, in_proj_b, out_proj_b,
                                          ln2_w, ln2_b, ff1_b, ff2_b,
                                          wb, flag, out);
    tsa_head<<<NCC / 32, 256, 0, stream>>>(count, o1_b, o2_b, wb, w256, out);
}